// Round 1
// baseline (425.037 us; speedup 1.0000x reference)
//
#include <hip/hip_runtime.h>

typedef _Float16 f16_t;
typedef _Float16 half8 __attribute__((ext_vector_type(8)));
typedef float f32x4 __attribute__((ext_vector_type(4)));
typedef unsigned short u16;

#define T_SEQ 2048
#define H_DIM 2048
#define C_DIM 1024
#define B_SZ  4

// async global->LDS, 16B per lane. LDS dest = wave-uniform base + lane*16.
__device__ __forceinline__ void gload16(const void* g, void* l) {
  typedef const __attribute__((address_space(1))) unsigned int* gp_t;
  typedef __attribute__((address_space(3))) unsigned int* lp_t;
  __builtin_amdgcn_global_load_lds((gp_t)(unsigned long long)g,
                                   (lp_t)(unsigned int)(unsigned long long)l,
                                   16, 0, 0);
}

// NT GEMM core: C[128,128] tile of A[M,K] * B[N,K]^T, lda=ldb=K, fp32 acc.
// 256 threads = 4 waves in 2x2, each wave 64x64 = 4x4 MFMA 16x16x32 f16 tiles.
__device__ __forceinline__ void gemm_tile(const f16_t* __restrict__ A,
                                          const f16_t* __restrict__ B,
                                          int K, int k_end, int m0, int n0,
                                          char* lds, f32x4 acc[4][4]) {
  const int tid  = threadIdx.x;
  const int wave = tid >> 6;
  const int lane = tid & 63;
  const int wm = (wave & 1) << 6;
  const int wn = (wave >> 1) << 6;
  const int srow = tid >> 2;         // 0..63: staging row
  const int scol = (tid & 3) << 3;   // 0,8,16,24: staging k-offset (8 f16 = 16B)
  const int fm = lane & 15;
  const int fk = (lane >> 4) << 3;
  const f16_t* As = (const f16_t*)lds;           // [128][32]
  const f16_t* Bs = (const f16_t*)(lds + 8192);  // [128][32]
  char* ldsA = lds + (wave << 10);               // wave-uniform base
  char* ldsB = lds + 8192 + (wave << 10);
  const f16_t* Ap0 = A + (size_t)(m0 + srow) * K + scol;
  const f16_t* Ap1 = A + (size_t)(m0 + 64 + srow) * K + scol;
  const f16_t* Bp0 = B + (size_t)(n0 + srow) * K + scol;
  const f16_t* Bp1 = B + (size_t)(n0 + 64 + srow) * K + scol;
  for (int k0 = 0; k0 < k_end; k0 += 32) {
    gload16(Ap0 + k0, ldsA);
    gload16(Ap1 + k0, ldsA + 4096);
    gload16(Bp0 + k0, ldsB);
    gload16(Bp1 + k0, ldsB + 4096);
    __syncthreads();   // drains vmcnt before s_barrier -> LDS valid
    half8 af[4], bfr[4];
#pragma unroll
    for (int i = 0; i < 4; ++i)
      af[i] = *(const half8*)(As + ((wm + i * 16 + fm) << 5) + fk);
#pragma unroll
    for (int j = 0; j < 4; ++j)
      bfr[j] = *(const half8*)(Bs + ((wn + j * 16 + fm) << 5) + fk);
#pragma unroll
    for (int i = 0; i < 4; ++i)
#pragma unroll
      for (int j = 0; j < 4; ++j)
        acc[i][j] = __builtin_amdgcn_mfma_f32_16x16x32_f16(af[i], bfr[j], acc[i][j], 0, 0, 0);
    __syncthreads();
  }
}

// C/D layout (verified m89): col = lane&15, row = (lane>>4)*4 + reg
#define EPI_PREAMBLE                                            \
  const int lane = threadIdx.x & 63;                            \
  const int wave = threadIdx.x >> 6;                            \
  const int mb = m0 + ((wave & 1) << 6) + ((lane >> 4) << 2);   \
  const int nb = n0 + ((wave >> 1) << 6) + (lane & 15);

#define ZERO_ACC                                                \
  f32x4 acc[4][4];                                              \
  _Pragma("unroll")                                             \
  for (int i = 0; i < 4; ++i)                                   \
    _Pragma("unroll")                                           \
    for (int j = 0; j < 4; ++j) acc[i][j] = (f32x4){0.f, 0.f, 0.f, 0.f};

// Q/K projection: C[m,n] = X[m,:] . W[n,:], store f16 row-major [M,N]
__global__ __launch_bounds__(256, 2)
void k_proj_qk(const f16_t* __restrict__ X, const f16_t* __restrict__ W,
               f16_t* __restrict__ Cb, int K, int N) {
  __shared__ char lds[16384];
  ZERO_ACC
  const int m0 = blockIdx.y << 7, n0 = blockIdx.x << 7;
  gemm_tile(X, W, K, K, m0, n0, lds, acc);
  EPI_PREAMBLE
#pragma unroll
  for (int i = 0; i < 4; ++i)
#pragma unroll
    for (int j = 0; j < 4; ++j) {
      const size_t base = (size_t)(mb + i * 16) * N + (nb + j * 16);
#pragma unroll
      for (int r = 0; r < 4; ++r)
        Cb[base + (size_t)r * N] = (f16_t)acc[i][j][r];
    }
}

// V projection, stored transposed per batch: Vt[b][h][t] (8B vector stores along t)
__global__ __launch_bounds__(256, 2)
void k_proj_v(const f16_t* __restrict__ X, const f16_t* __restrict__ W,
              u16* __restrict__ Vt, int K) {
  __shared__ char lds[16384];
  ZERO_ACC
  const int m0 = blockIdx.y << 7, n0 = blockIdx.x << 7;
  gemm_tile(X, W, K, K, m0, n0, lds, acc);
  EPI_PREAMBLE
#pragma unroll
  for (int i = 0; i < 4; ++i) {
    const int gm = mb + i * 16;          // global row = b*T + t (r=0)
    const int b = gm >> 11;
    const int t = gm & (T_SEQ - 1);
#pragma unroll
    for (int j = 0; j < 4; ++j) {
      const int h = nb + j * 16;
      ushort4 pk;
      pk.x = __builtin_bit_cast(u16, (f16_t)acc[i][j][0]);
      pk.y = __builtin_bit_cast(u16, (f16_t)acc[i][j][1]);
      pk.z = __builtin_bit_cast(u16, (f16_t)acc[i][j][2]);
      pk.w = __builtin_bit_cast(u16, (f16_t)acc[i][j][3]);
      *(ushort4*)(Vt + ((size_t)(b * H_DIM + h) * T_SEQ + t)) = pk;
    }
  }
}

// scores: S[b][t][s] = (q . k) * H^-0.5, fp32. Blocks above diagonal skipped;
// softmax only reads cols <= row so no mask writes needed.
__global__ __launch_bounds__(256, 2)
void k_scores(const f16_t* __restrict__ Q, const f16_t* __restrict__ Kc,
              float* __restrict__ S) {
  if (blockIdx.x > blockIdx.y) return;   // strictly upper tile
  __shared__ char lds[16384];
  ZERO_ACC
  const int b = blockIdx.z;
  const int m0 = blockIdx.y << 7, n0 = blockIdx.x << 7;
  const f16_t* Aq = Q + (size_t)b * T_SEQ * H_DIM;
  const f16_t* Bk = Kc + (size_t)b * T_SEQ * H_DIM;
  float* Sb = S + (size_t)b * T_SEQ * T_SEQ;
  gemm_tile(Aq, Bk, H_DIM, H_DIM, m0, n0, lds, acc);
  EPI_PREAMBLE
  const float scale = 0.022097086912079608f;  // 2048^-0.5
#pragma unroll
  for (int i = 0; i < 4; ++i)
#pragma unroll
    for (int j = 0; j < 4; ++j) {
      const size_t base = (size_t)(mb + i * 16) * T_SEQ + (nb + j * 16);
#pragma unroll
      for (int r = 0; r < 4; ++r)
        Sb[base + (size_t)r * T_SEQ] = acc[i][j][r] * scale;
    }
}

// causal softmax row-wise: S fp32 -> P f16 (zeros above diagonal)
__global__ __launch_bounds__(256)
void k_softmax(const float* __restrict__ S, f16_t* __restrict__ P) {
  const int row = blockIdx.x;            // b*T + t
  const int t = row & (T_SEQ - 1);
  const int n = t + 1;                   // valid columns
  const int tid = threadIdx.x;
  const float* s = S + (size_t)row * T_SEQ;
  f16_t* p = P + (size_t)row * T_SEQ;
  __shared__ float buf[T_SEQ];
  __shared__ float red[8];
  float lmax = -3.0e38f;
  for (int c = tid; c < n; c += 256) lmax = fmaxf(lmax, s[c]);
#pragma unroll
  for (int off = 32; off > 0; off >>= 1) lmax = fmaxf(lmax, __shfl_xor(lmax, off, 64));
  if ((tid & 63) == 0) red[tid >> 6] = lmax;
  __syncthreads();
  const float m = fmaxf(fmaxf(red[0], red[1]), fmaxf(red[2], red[3]));
  float lsum = 0.f;
  for (int c = tid; c < n; c += 256) {
    float e = __expf(s[c] - m);
    buf[c] = e;
    lsum += e;
  }
#pragma unroll
  for (int off = 32; off > 0; off >>= 1) lsum += __shfl_xor(lsum, off, 64);
  if ((tid & 63) == 0) red[4 + (tid >> 6)] = lsum;
  __syncthreads();
  const float inv = 1.0f / (red[4] + red[5] + red[6] + red[7]);
  for (int c = tid; c < T_SEQ; c += 256)
    p[c] = (c < n) ? (f16_t)(buf[c] * inv) : (f16_t)0.f;
}

// PV: Out[b][t][h] = sum_s P[t][s] * Vt[h][s]; K-loop capped at diagonal tile.
__global__ __launch_bounds__(256, 2)
void k_pv(const f16_t* __restrict__ P, const f16_t* __restrict__ Vt,
          float* __restrict__ Out) {
  __shared__ char lds[16384];
  ZERO_ACC
  const int b = blockIdx.z;
  const int m0 = blockIdx.y << 7, n0 = blockIdx.x << 7;
  const int k_end = m0 + 128;   // P[t][s]==0 for s>t
  const f16_t* Ap = P + (size_t)b * T_SEQ * T_SEQ;
  const f16_t* Bv = Vt + (size_t)b * H_DIM * T_SEQ;
  float* Ob = Out + (size_t)b * T_SEQ * H_DIM;
  gemm_tile(Ap, Bv, T_SEQ, k_end, m0, n0, lds, acc);
  EPI_PREAMBLE
#pragma unroll
  for (int i = 0; i < 4; ++i)
#pragma unroll
    for (int j = 0; j < 4; ++j) {
      const size_t base = (size_t)(mb + i * 16) * H_DIM + (nb + j * 16);
#pragma unroll
      for (int r = 0; r < 4; ++r)
        Ob[base + (size_t)r * H_DIM] = acc[i][j][r];
    }
}

__global__ __launch_bounds__(256)
void k_cvt(const float4* __restrict__ src, ushort4* __restrict__ dst, int n4) {
  const int i = blockIdx.x * 256 + threadIdx.x;
  if (i >= n4) return;
  const float4 v = src[i];
  ushort4 o;
  o.x = __builtin_bit_cast(u16, (f16_t)v.x);
  o.y = __builtin_bit_cast(u16, (f16_t)v.y);
  o.z = __builtin_bit_cast(u16, (f16_t)v.z);
  o.w = __builtin_bit_cast(u16, (f16_t)v.w);
  dst[i] = o;
}

extern "C" void kernel_launch(void* const* d_in, const int* in_sizes, int n_in,
                              void* d_out, int out_size, void* d_ws, size_t ws_size,
                              hipStream_t stream) {
  (void)in_sizes; (void)n_in; (void)out_size; (void)ws_size;
  const float* x  = (const float*)d_in[0];
  const float* Wk = (const float*)d_in[1];
  const float* Wq = (const float*)d_in[2];
  const float* Wv = (const float*)d_in[3];
  float* out = (float*)d_out;
  char* ws = (char*)d_ws;
  // workspace layout (bytes):
  //  [0,32M)   q f16 [B*T,H]          [32M,64M)  k f16
  //  [64M,96M) Vt f16 [B,H,T]         [96M,160M) S fp32 [B,T,T]
  //  [160M,192M) P f16 [B,T,T]
  //  converts (freed before scores overwrite): xb@96M, w*b@112M..124M
  f16_t* qb  = (f16_t*)(ws);
  f16_t* kb  = (f16_t*)(ws + (32ull << 20));
  f16_t* vt  = (f16_t*)(ws + (64ull << 20));
  float* S   = (float*)(ws + (96ull << 20));
  f16_t* P   = (f16_t*)(ws + (160ull << 20));
  f16_t* xb  = (f16_t*)(ws + (96ull << 20));
  f16_t* wkb = (f16_t*)(ws + (112ull << 20));
  f16_t* wqb = (f16_t*)(ws + (116ull << 20));
  f16_t* wvb = (f16_t*)(ws + (120ull << 20));

  k_cvt<<<(B_SZ * T_SEQ * C_DIM) / 1024, 256, 0, stream>>>((const float4*)x, (ushort4*)xb, (B_SZ * T_SEQ * C_DIM) / 4);
  k_cvt<<<(H_DIM * C_DIM) / 1024, 256, 0, stream>>>((const float4*)Wk, (ushort4*)wkb, (H_DIM * C_DIM) / 4);
  k_cvt<<<(H_DIM * C_DIM) / 1024, 256, 0, stream>>>((const float4*)Wq, (ushort4*)wqb, (H_DIM * C_DIM) / 4);
  k_cvt<<<(H_DIM * C_DIM) / 1024, 256, 0, stream>>>((const float4*)Wv, (ushort4*)wvb, (H_DIM * C_DIM) / 4);

  dim3 gp(H_DIM / 128, (B_SZ * T_SEQ) / 128);          // 16 x 64
  k_proj_qk<<<gp, 256, 0, stream>>>(xb, wqb, qb, C_DIM, H_DIM);
  k_proj_qk<<<gp, 256, 0, stream>>>(xb, wkb, kb, C_DIM, H_DIM);
  k_proj_v <<<gp, 256, 0, stream>>>(xb, wvb, (u16*)vt, C_DIM);

  dim3 gs(T_SEQ / 128, T_SEQ / 128, B_SZ);             // 16 x 16 x 4
  k_scores<<<gs, 256, 0, stream>>>(qb, kb, S);
  k_softmax<<<B_SZ * T_SEQ, 256, 0, stream>>>(S, P);
  k_pv<<<gs, 256, 0, stream>>>(P, vt, out);
}

// Round 2
// 416.717 us; speedup vs baseline: 1.0200x; 1.0200x over previous
//
#include <hip/hip_runtime.h>
#include <math.h>

typedef _Float16 f16_t;
typedef _Float16 half8 __attribute__((ext_vector_type(8)));
typedef float f32x4 __attribute__((ext_vector_type(4)));
typedef unsigned short u16;

#define T_SEQ 2048
#define H_DIM 2048
#define C_DIM 1024
#define B_SZ  4

// async global->LDS, 16B per lane. LDS dest = wave-uniform base + lane*16.
__device__ __forceinline__ void gload16(const void* g, void* l) {
  typedef const __attribute__((address_space(1))) unsigned int* gp_t;
  typedef __attribute__((address_space(3))) unsigned int* lp_t;
  __builtin_amdgcn_global_load_lds((gp_t)(unsigned long long)g,
                                   (lp_t)(unsigned int)(unsigned long long)l,
                                   16, 0, 0);
}

// ---------------- 4-wave core (256 thr): 128x128 tile, BK=32 ----------------
__device__ __forceinline__ void gemm_tile(const f16_t* __restrict__ A,
                                          const f16_t* __restrict__ B,
                                          int K, int k_end, int m0, int n0,
                                          char* lds, f32x4 acc[4][4]) {
  const int tid  = threadIdx.x;
  const int wave = tid >> 6;
  const int lane = tid & 63;
  const int wm = (wave & 1) << 6;
  const int wn = (wave >> 1) << 6;
  const int srow = tid >> 2;
  const int scol = (tid & 3) << 3;
  const int fm = lane & 15;
  const int fk = (lane >> 4) << 3;
  const f16_t* As = (const f16_t*)lds;           // [128][32]
  const f16_t* Bs = (const f16_t*)(lds + 8192);  // [128][32]
  char* ldsA = lds + (wave << 10);
  char* ldsB = lds + 8192 + (wave << 10);
  const f16_t* Ap0 = A + (size_t)(m0 + srow) * K + scol;
  const f16_t* Ap1 = A + (size_t)(m0 + 64 + srow) * K + scol;
  const f16_t* Bp0 = B + (size_t)(n0 + srow) * K + scol;
  const f16_t* Bp1 = B + (size_t)(n0 + 64 + srow) * K + scol;
  for (int k0 = 0; k0 < k_end; k0 += 32) {
    gload16(Ap0 + k0, ldsA);
    gload16(Ap1 + k0, ldsA + 4096);
    gload16(Bp0 + k0, ldsB);
    gload16(Bp1 + k0, ldsB + 4096);
    __syncthreads();
    half8 af[4], bfr[4];
#pragma unroll
    for (int i = 0; i < 4; ++i)
      af[i] = *(const half8*)(As + ((wm + i * 16 + fm) << 5) + fk);
#pragma unroll
    for (int j = 0; j < 4; ++j)
      bfr[j] = *(const half8*)(Bs + ((wn + j * 16 + fm) << 5) + fk);
#pragma unroll
    for (int i = 0; i < 4; ++i)
#pragma unroll
      for (int j = 0; j < 4; ++j)
        acc[i][j] = __builtin_amdgcn_mfma_f32_16x16x32_f16(af[i], bfr[j], acc[i][j], 0, 0, 0);
    __syncthreads();
  }
}

// ------- 8-wave split-K core (512 thr): two groups halve K, LDS-reduce ------
// lds must be 32 KB. After return, waves 0-3 (grp 0) hold the full sums.
__device__ __forceinline__ void gemm_tile_sk2(const f16_t* __restrict__ A,
                                              const f16_t* __restrict__ B,
                                              int K, int k_end, int m0, int n0,
                                              char* lds, f32x4 acc[4][4]) {
  const int tid  = threadIdx.x;            // 0..511
  const int grp  = tid >> 8;               // 0,1  (waves 0-3 / 4-7)
  const int ltid = tid & 255;
  const int wl   = ltid >> 6;              // local wave 0..3
  const int lane = tid & 63;
  const int wm = (wl & 1) << 6;
  const int wn = (wl >> 1) << 6;
  const int srow = ltid >> 2;
  const int scol = (ltid & 3) << 3;
  const int fm = lane & 15;
  const int fk = (lane >> 4) << 3;
  const int half = k_end >> 1;             // multiple of 64
  const f16_t* As = (const f16_t*)(lds + grp * 16384);
  const f16_t* Bs = (const f16_t*)(lds + grp * 16384 + 8192);
  char* ldsA = lds + grp * 16384 + (wl << 10);
  char* ldsB = lds + grp * 16384 + 8192 + (wl << 10);
  const int kb = grp * half;
  const f16_t* Ap0 = A + (size_t)(m0 + srow) * K + kb + scol;
  const f16_t* Ap1 = A + (size_t)(m0 + 64 + srow) * K + kb + scol;
  const f16_t* Bp0 = B + (size_t)(n0 + srow) * K + kb + scol;
  const f16_t* Bp1 = B + (size_t)(n0 + 64 + srow) * K + kb + scol;
  for (int k0 = 0; k0 < half; k0 += 32) {
    gload16(Ap0 + k0, ldsA);
    gload16(Ap1 + k0, ldsA + 4096);
    gload16(Bp0 + k0, ldsB);
    gload16(Bp1 + k0, ldsB + 4096);
    __syncthreads();
    half8 af[4], bfr[4];
#pragma unroll
    for (int i = 0; i < 4; ++i)
      af[i] = *(const half8*)(As + ((wm + i * 16 + fm) << 5) + fk);
#pragma unroll
    for (int j = 0; j < 4; ++j)
      bfr[j] = *(const half8*)(Bs + ((wn + j * 16 + fm) << 5) + fk);
#pragma unroll
    for (int i = 0; i < 4; ++i)
#pragma unroll
      for (int j = 0; j < 4; ++j)
        acc[i][j] = __builtin_amdgcn_mfma_f32_16x16x32_f16(af[i], bfr[j], acc[i][j], 0, 0, 0);
    __syncthreads();
  }
  // Reduce grp1 partials into grp0. Two rounds of 2 quads (2 x 16 KB in LDS).
  float* red = (float*)lds;
#pragma unroll
  for (int round = 0; round < 2; ++round) {
    const int q0 = round << 1;
    if (grp == 1 && (wl == q0 || wl == q0 + 1)) {
      float* dst = red + (wl - q0) * 4096;
#pragma unroll
      for (int i = 0; i < 4; ++i)
#pragma unroll
        for (int j = 0; j < 4; ++j)
          *(f32x4*)(dst + (((i << 2) + j) << 8) + (lane << 2)) = acc[i][j];
    }
    __syncthreads();
    if (grp == 0 && (wl == q0 || wl == q0 + 1)) {
      const float* src = red + (wl - q0) * 4096;
#pragma unroll
      for (int i = 0; i < 4; ++i)
#pragma unroll
        for (int j = 0; j < 4; ++j) {
          const f32x4 p = *(const f32x4*)(src + (((i << 2) + j) << 8) + (lane << 2));
          acc[i][j] += p;
        }
    }
    __syncthreads();
  }
}

// C/D layout (verified m89): col = lane&15, row = (lane>>4)*4 + reg
#define EPI_PREAMBLE                                            \
  const int lane = threadIdx.x & 63;                            \
  const int wl_e = (threadIdx.x >> 6) & 3;                      \
  const int mb = m0 + ((wl_e & 1) << 6) + ((lane >> 4) << 2);   \
  const int nb = n0 + ((wl_e >> 1) << 6) + (lane & 15);

#define ZERO_ACC                                                \
  f32x4 acc[4][4];                                              \
  _Pragma("unroll")                                             \
  for (int i = 0; i < 4; ++i)                                   \
    _Pragma("unroll")                                           \
    for (int j = 0; j < 4; ++j) acc[i][j] = (f32x4){0.f, 0.f, 0.f, 0.f};

// Merged Q/K/V projection: z=0 -> Q, z=1 -> K (row-major f16), z=2 -> V^T
__global__ __launch_bounds__(256, 2)
void k_proj(const f16_t* __restrict__ X,
            const f16_t* __restrict__ Wq, const f16_t* __restrict__ Wk,
            const f16_t* __restrict__ Wv,
            f16_t* __restrict__ Qo, f16_t* __restrict__ Ko,
            u16* __restrict__ Vt) {
  __shared__ char lds[16384];
  ZERO_ACC
  const int z = blockIdx.z;
  const f16_t* W = (z == 0) ? Wq : (z == 1) ? Wk : Wv;
  const int m0 = blockIdx.y << 7, n0 = blockIdx.x << 7;
  gemm_tile(X, W, C_DIM, C_DIM, m0, n0, lds, acc);
  EPI_PREAMBLE
  if (z < 2) {
    f16_t* Cb = z ? Ko : Qo;
#pragma unroll
    for (int i = 0; i < 4; ++i)
#pragma unroll
      for (int j = 0; j < 4; ++j) {
        const size_t base = (size_t)(mb + i * 16) * H_DIM + (nb + j * 16);
#pragma unroll
        for (int r = 0; r < 4; ++r)
          Cb[base + (size_t)r * H_DIM] = (f16_t)acc[i][j][r];
      }
  } else {
#pragma unroll
    for (int i = 0; i < 4; ++i) {
      const int gm = mb + i * 16;          // b*T + t
      const int b = gm >> 11;
      const int t = gm & (T_SEQ - 1);
#pragma unroll
      for (int j = 0; j < 4; ++j) {
        const int h = nb + j * 16;
        ushort4 pk;
        pk.x = __builtin_bit_cast(u16, (f16_t)acc[i][j][0]);
        pk.y = __builtin_bit_cast(u16, (f16_t)acc[i][j][1]);
        pk.z = __builtin_bit_cast(u16, (f16_t)acc[i][j][2]);
        pk.w = __builtin_bit_cast(u16, (f16_t)acc[i][j][3]);
        *(ushort4*)(Vt + ((size_t)(b * H_DIM + h) * T_SEQ + t)) = pk;
      }
    }
  }
}

// scores: lower-triangle tiles only, 8-wave split-K. S fp32 (scaled).
__global__ __launch_bounds__(512, 4)
void k_scores(const f16_t* __restrict__ Q, const f16_t* __restrict__ Kc,
              float* __restrict__ S) {
  __shared__ char lds[32768];
  ZERO_ACC
  const int p = blockIdx.x;                // 0..135 lower-triangle tile id
  int i = (int)((sqrtf(8.f * p + 1.f) - 1.f) * 0.5f);
  while ((i + 1) * (i + 2) / 2 <= p) ++i;
  while (i * (i + 1) / 2 > p) --i;
  const int j = p - i * (i + 1) / 2;
  const int b = blockIdx.y;
  const int m0 = i << 7, n0 = j << 7;
  const f16_t* Aq = Q + (size_t)b * T_SEQ * H_DIM;
  const f16_t* Bk = Kc + (size_t)b * T_SEQ * H_DIM;
  float* Sb = S + (size_t)b * T_SEQ * T_SEQ;
  gemm_tile_sk2(Aq, Bk, H_DIM, H_DIM, m0, n0, lds, acc);
  if (threadIdx.x >> 8) return;            // grp1 has no sums
  EPI_PREAMBLE
  const float scale = 0.022097086912079608f;  // 2048^-0.5
#pragma unroll
  for (int i2 = 0; i2 < 4; ++i2)
#pragma unroll
    for (int j2 = 0; j2 < 4; ++j2) {
      const size_t base = (size_t)(mb + i2 * 16) * T_SEQ + (nb + j2 * 16);
#pragma unroll
      for (int r = 0; r < 4; ++r)
        Sb[base + (size_t)r * T_SEQ] = acc[i2][j2][r] * scale;
    }
}

// causal softmax row-wise: S fp32 -> P f16 (zeros above diagonal)
__global__ __launch_bounds__(256)
void k_softmax(const float* __restrict__ S, f16_t* __restrict__ P) {
  const int row = blockIdx.x;              // b*T + t
  const int t = row & (T_SEQ - 1);
  const int n = t + 1;
  const int tid = threadIdx.x;
  const float* s = S + (size_t)row * T_SEQ;
  f16_t* p = P + (size_t)row * T_SEQ;
  __shared__ float buf[T_SEQ];
  __shared__ float red[8];
  float lmax = -3.0e38f;
  for (int c = tid; c < n; c += 256) lmax = fmaxf(lmax, s[c]);
#pragma unroll
  for (int off = 32; off > 0; off >>= 1) lmax = fmaxf(lmax, __shfl_xor(lmax, off, 64));
  if ((tid & 63) == 0) red[tid >> 6] = lmax;
  __syncthreads();
  const float m = fmaxf(fmaxf(red[0], red[1]), fmaxf(red[2], red[3]));
  float lsum = 0.f;
  for (int c = tid; c < n; c += 256) {
    float e = __expf(s[c] - m);
    buf[c] = e;
    lsum += e;
  }
#pragma unroll
  for (int off = 32; off > 0; off >>= 1) lsum += __shfl_xor(lsum, off, 64);
  if ((tid & 63) == 0) red[4 + (tid >> 6)] = lsum;
  __syncthreads();
  const float inv = 1.0f / (red[4] + red[5] + red[6] + red[7]);
  for (int c = tid; c < T_SEQ; c += 256)
    p[c] = (c < n) ? (f16_t)(buf[c] * inv) : (f16_t)0.f;
}

// PV: Out[b][t][h] = sum_s P[t][s] * Vt[h][s]; split-K, longest tiles first.
__global__ __launch_bounds__(512, 4)
void k_pv(const f16_t* __restrict__ P, const f16_t* __restrict__ Vt,
          float* __restrict__ Out) {
  __shared__ char lds[32768];
  ZERO_ACC
  const int b = blockIdx.z;
  const int m0 = (int)(gridDim.y - 1 - blockIdx.y) << 7;  // big K first
  const int n0 = blockIdx.x << 7;
  const int k_end = m0 + 128;              // P[t][s]==0 for s>t
  const f16_t* Ap = P + (size_t)b * T_SEQ * T_SEQ;
  const f16_t* Bv = Vt + (size_t)b * H_DIM * T_SEQ;
  float* Ob = Out + (size_t)b * T_SEQ * H_DIM;
  gemm_tile_sk2(Ap, Bv, T_SEQ, k_end, m0, n0, lds, acc);
  if (threadIdx.x >> 8) return;
  EPI_PREAMBLE
#pragma unroll
  for (int i = 0; i < 4; ++i)
#pragma unroll
    for (int j = 0; j < 4; ++j) {
      const size_t base = (size_t)(mb + i * 16) * H_DIM + (nb + j * 16);
#pragma unroll
      for (int r = 0; r < 4; ++r)
        Ob[base + (size_t)r * H_DIM] = acc[i][j][r];
    }
}

// one fused f32 -> f16 conversion pass over x, Wk, Wq, Wv
#define XN4 ((B_SZ * T_SEQ * C_DIM) / 4)   // 2097152
#define WN4 ((H_DIM * C_DIM) / 4)          // 524288
__global__ __launch_bounds__(256)
void k_cvt_all(const float4* __restrict__ x,  const float4* __restrict__ wk,
               const float4* __restrict__ wq, const float4* __restrict__ wv,
               ushort4* __restrict__ xb, ushort4* __restrict__ wkb,
               ushort4* __restrict__ wqb, ushort4* __restrict__ wvb) {
  int idx = blockIdx.x * 256 + threadIdx.x;
  const float4* src; ushort4* dst;
  if (idx < XN4)                { src = x;  dst = xb; }
  else if (idx < XN4 + WN4)     { src = wk; dst = wkb; idx -= XN4; }
  else if (idx < XN4 + 2 * WN4) { src = wq; dst = wqb; idx -= XN4 + WN4; }
  else                          { src = wv; dst = wvb; idx -= XN4 + 2 * WN4; }
  const float4 v = src[idx];
  ushort4 o;
  o.x = __builtin_bit_cast(u16, (f16_t)v.x);
  o.y = __builtin_bit_cast(u16, (f16_t)v.y);
  o.z = __builtin_bit_cast(u16, (f16_t)v.z);
  o.w = __builtin_bit_cast(u16, (f16_t)v.w);
  dst[idx] = o;
}

extern "C" void kernel_launch(void* const* d_in, const int* in_sizes, int n_in,
                              void* d_out, int out_size, void* d_ws, size_t ws_size,
                              hipStream_t stream) {
  (void)in_sizes; (void)n_in; (void)out_size; (void)ws_size;
  const float* x  = (const float*)d_in[0];
  const float* Wk = (const float*)d_in[1];
  const float* Wq = (const float*)d_in[2];
  const float* Wv = (const float*)d_in[3];
  float* out = (float*)d_out;
  char* ws = (char*)d_ws;
  // workspace (192 MB):
  //  [0,32M) q f16   [32M,64M) k f16   [64M,96M) Vt f16 [B,H,T]
  //  [96M,160M) S fp32 [B,T,T]         [160M,192M) P f16
  //  cvt temps (dead before S written): xb@96M, wk@112M, wq@116M, wv@120M
  f16_t* qb  = (f16_t*)(ws);
  f16_t* kb  = (f16_t*)(ws + (32ull << 20));
  f16_t* vt  = (f16_t*)(ws + (64ull << 20));
  float* S   = (float*)(ws + (96ull << 20));
  f16_t* P   = (f16_t*)(ws + (160ull << 20));
  f16_t* xb  = (f16_t*)(ws + (96ull << 20));
  f16_t* wkb = (f16_t*)(ws + (112ull << 20));
  f16_t* wqb = (f16_t*)(ws + (116ull << 20));
  f16_t* wvb = (f16_t*)(ws + (120ull << 20));

  k_cvt_all<<<(XN4 + 3 * WN4) / 256, 256, 0, stream>>>(
      (const float4*)x, (const float4*)Wk, (const float4*)Wq, (const float4*)Wv,
      (ushort4*)xb, (ushort4*)wkb, (ushort4*)wqb, (ushort4*)wvb);

  dim3 gp(H_DIM / 128, (B_SZ * T_SEQ) / 128, 3);       // 16 x 64 x 3
  k_proj<<<gp, 256, 0, stream>>>(xb, wqb, wkb, wvb, qb, kb, (u16*)vt);

  dim3 gs(136, B_SZ);                                   // lower-triangle tiles
  k_scores<<<gs, 512, 0, stream>>>(qb, kb, S);
  k_softmax<<<B_SZ * T_SEQ, 256, 0, stream>>>(S, P);
  dim3 gv(T_SEQ / 128, T_SEQ / 128, B_SZ);              // 16 x 16 x 4
  k_pv<<<gv, 512, 0, stream>>>(P, vt, out);
}